// Round 10
// baseline (202.328 us; speedup 1.0000x reference)
//
#include <hip/hip_runtime.h>
#include <hip/hip_fp16.h>

// GCN, 4 layers, improved=True (self-loop weight 2.0), symmetric norm.
// N=50000 nodes, E=800000 edges, dims 16 -> 128 -> 128 -> 128 -> 16.
//
// R10: gather+GEMM fusion. Each 64-row block gathers its nodes into a
// swizzled fp16 LDS tile (the MFMA A layout proven in R9's x1s) and runs
// the MFMA in the same kernel -- the Ah hand-off buffer and 4 launches
// disappear. Pipeline (7 kernels):
//   prep(init cnt + wt fp16-swizzle) -> fill -> row_deg_xscale(gA=xs)
//   fused_l0l1: gather16(gA)->a0(LDS,fp32), VALU K=16 GEMM -> x1s, MFMA@wt1 -> gB
//   fgm128:     gather128(gB,+b1,relu)->tile, MFMA@wt2 -> gA
//   fgm16:      gather128(gA,+b2,relu)->tile, MFMA@wt3 -> gB (16ch)
//   gather16_final(gB,+b3) -> out fp32

static constexpr int NN = 50000;
static constexpr int NE = 800000;
static constexpr int RSTRIDE = 72;  // int2 per row: [cnt|pad][71 entry slots]

typedef _Float16 half8_t __attribute__((ext_vector_type(8)));
typedef float float4_t __attribute__((ext_vector_type(4)));

union Frag { uint4 u; half8_t h; };
union H2U2 { uint2 u; __half2 h[2]; };
union H4U4 { uint4 u; __half2 h[4]; };

// ---------------------------------------------------------------- build

// zero csr counters + convert w1/w2/w3 to fp16 transposed [n][k] XOR-swizzled
__global__ void prep_kernel(const float* __restrict__ w1, const float* __restrict__ w2,
                            const float* __restrict__ w3, char* __restrict__ wt1,
                            char* __restrict__ wt2, char* __restrict__ wt3,
                            int2* __restrict__ csr) {
  int t = blockIdx.x * blockDim.x + threadIdx.x;
  if (t < NN) ((int*)(csr + (size_t)t * RSTRIDE))[0] = 0;
  if (t < 16384) {
    int k = t >> 7, n = t & 127;
    int off = n * 256 + ((2 * k) ^ ((n & 7) << 4));
    *(ushort*)(wt1 + off) = __half_as_ushort(__float2half(w1[t]));
    *(ushort*)(wt2 + off) = __half_as_ushort(__float2half(w2[t]));
  }
  if (t < 2048) {
    int k = t >> 4, n = t & 15;
    *(ushort*)(wt3 + n * 256 + ((2 * k) ^ ((n & 7) << 4))) = __half_as_ushort(__float2half(w3[t]));
  }
}

__global__ void fill_pad_kernel(const int* __restrict__ src, const int* __restrict__ dst,
                                const float* __restrict__ ea, int2* __restrict__ csr, int ne) {
  int i = blockIdx.x * blockDim.x + threadIdx.x;
  if (i < ne) {
    int d = dst[i];
    int slot = atomicAdd((int*)(csr + (size_t)d * RSTRIDE), 1);
    csr[(size_t)d * RSTRIDE + 1 + slot] = make_int2(src[i], __float_as_int(ea[i]));
  }
}

// dinv[i] = rsqrt(2 + sum row weights); xs[i][:] = dinv[i] * x[i][:] (fp16)
__global__ void row_deg_xscale_kernel(const int2* __restrict__ csr, const float* __restrict__ x,
                                      float* __restrict__ dinv, __half* __restrict__ xs, int n) {
  int i = blockIdx.x * blockDim.x + threadIdx.x;
  if (i >= n) return;
  const int2* row = csr + (size_t)i * RSTRIDE;
  int cn = ((const int*)row)[0];
  float d = 2.0f;
  for (int e = 1; e <= cn; ++e) d += __int_as_float(row[e].y);
  float dn = rsqrtf(d);  // d >= 2 always (ea >= 0)
  dinv[i] = dn;
  const float4* xr = (const float4*)(x + (size_t)i * 16);
  uint2* xo = (uint2*)(xs + (size_t)i * 16);
#pragma unroll
  for (int q = 0; q < 4; ++q) {
    float4 v = xr[q];
    H2U2 pk;
    pk.h[0] = __float22half2_rn(make_float2(dn * v.x, dn * v.y));
    pk.h[1] = __float22half2_rn(make_float2(dn * v.z, dn * v.w));
    xo[q] = pk.u;
  }
}

// ---------------------------------------------------------------- gather helpers

// accumulate sum_e w_e * g[src][cg*8..+7] into acc[8] (fp16 rows of 16 uint4)
__device__ __forceinline__ void gacc128(const uint4* __restrict__ g4, const int2* __restrict__ row,
                                        int cn, int cg, float acc[8]) {
  int e = 0;
  for (; e + 4 <= cn; e += 4) {
    int2 ed[4];
#pragma unroll
    for (int j = 0; j < 4; ++j) ed[j] = row[1 + e + j];
    H4U4 v[4];
#pragma unroll
    for (int j = 0; j < 4; ++j) v[j].u = g4[(size_t)ed[j].x * 16 + cg];
#pragma unroll
    for (int j = 0; j < 4; ++j) {
      float w = __int_as_float(ed[j].y);
      float2 f0 = __half22float2(v[j].h[0]), f1 = __half22float2(v[j].h[1]);
      float2 f2 = __half22float2(v[j].h[2]), f3 = __half22float2(v[j].h[3]);
      acc[0] = fmaf(w, f0.x, acc[0]); acc[1] = fmaf(w, f0.y, acc[1]);
      acc[2] = fmaf(w, f1.x, acc[2]); acc[3] = fmaf(w, f1.y, acc[3]);
      acc[4] = fmaf(w, f2.x, acc[4]); acc[5] = fmaf(w, f2.y, acc[5]);
      acc[6] = fmaf(w, f3.x, acc[6]); acc[7] = fmaf(w, f3.y, acc[7]);
    }
  }
  for (; e < cn; ++e) {
    int2 ed = row[1 + e];
    H4U4 v; v.u = g4[(size_t)ed.x * 16 + cg];
    float w = __int_as_float(ed.y);
    float2 f0 = __half22float2(v.h[0]), f1 = __half22float2(v.h[1]);
    float2 f2 = __half22float2(v.h[2]), f3 = __half22float2(v.h[3]);
    acc[0] = fmaf(w, f0.x, acc[0]); acc[1] = fmaf(w, f0.y, acc[1]);
    acc[2] = fmaf(w, f1.x, acc[2]); acc[3] = fmaf(w, f1.y, acc[3]);
    acc[4] = fmaf(w, f2.x, acc[4]); acc[5] = fmaf(w, f2.y, acc[5]);
    acc[6] = fmaf(w, f3.x, acc[6]); acc[7] = fmaf(w, f3.y, acc[7]);
  }
}

// gather 64 nodes (C=128) of row0.. into swizzled fp16 LDS tile, epilogue relu(dinv*acc+bias)
__device__ __forceinline__ void gather_tile128(const __half* __restrict__ g,
                                               const int2* __restrict__ csr,
                                               const float* __restrict__ dinv,
                                               const float* __restrict__ bias,
                                               char* __restrict__ tile, int row0, int n) {
  const int sub = threadIdx.x >> 4;  // 0..15
  const int cg = threadIdx.x & 15;
  const uint4* g4 = (const uint4*)g;
  const float4* b4 = (const float4*)bias;
  const float4 bl = b4[cg * 2], bh = b4[cg * 2 + 1];
#pragma unroll
  for (int it = 0; it < 4; ++it) {
    const int r = it * 16 + sub;
    const int node = row0 + r;
    H4U4 pk; pk.u = make_uint4(0u, 0u, 0u, 0u);
    if (node < n) {
      float acc[8];
      H4U4 self; self.u = g4[(size_t)node * 16 + cg];
      float2 f0 = __half22float2(self.h[0]), f1 = __half22float2(self.h[1]);
      float2 f2 = __half22float2(self.h[2]), f3 = __half22float2(self.h[3]);
      acc[0] = 2.f * f0.x; acc[1] = 2.f * f0.y; acc[2] = 2.f * f1.x; acc[3] = 2.f * f1.y;
      acc[4] = 2.f * f2.x; acc[5] = 2.f * f2.y; acc[6] = 2.f * f3.x; acc[7] = 2.f * f3.y;
      const int2* row = csr + (size_t)node * RSTRIDE;
      const int cn = ((const int*)row)[0];
      gacc128(g4, row, cn, cg, acc);
      const float dn = dinv[node];
      float r0 = fmaxf(dn * acc[0] + bl.x, 0.f), r1 = fmaxf(dn * acc[1] + bl.y, 0.f);
      float r2 = fmaxf(dn * acc[2] + bl.z, 0.f), r3 = fmaxf(dn * acc[3] + bl.w, 0.f);
      float r4 = fmaxf(dn * acc[4] + bh.x, 0.f), r5 = fmaxf(dn * acc[5] + bh.y, 0.f);
      float r6 = fmaxf(dn * acc[6] + bh.z, 0.f), r7 = fmaxf(dn * acc[7] + bh.w, 0.f);
      pk.h[0] = __float22half2_rn(make_float2(r0, r1));
      pk.h[1] = __float22half2_rn(make_float2(r2, r3));
      pk.h[2] = __float22half2_rn(make_float2(r4, r5));
      pk.h[3] = __float22half2_rn(make_float2(r6, r7));
    }
    *(uint4*)(tile + r * 256 + ((cg * 16) ^ ((r & 7) << 4))) = pk.u;
  }
}

// ---------------------------------------------------------------- fused kernels

// gather128(g,+bias,relu) -> tile ; MFMA tile @ wt (128x128) -> outg = dinv.(..)
__global__ void __launch_bounds__(256) fgm128_kernel(
    const __half* __restrict__ g, const int2* __restrict__ csr, const float* __restrict__ dinv,
    const float* __restrict__ bias, const char* __restrict__ wt, __half* __restrict__ outg, int n) {
  __shared__ char wts[32768];
  __shared__ char tile[16384];
  for (int i = threadIdx.x; i < 2048; i += 256)
    ((uint4*)wts)[i] = ((const uint4*)wt)[i];
  const int row0 = blockIdx.x * 64;
  gather_tile128(g, csr, dinv, bias, tile, row0, n);
  __syncthreads();

  const int wave = threadIdx.x >> 6, lane = threadIdx.x & 63;
  const int lr = lane & 15, hi = lane >> 4;
  const int rowL = wave * 16 + lr;
  const char* Arow = tile + rowL * 256;
  const int swa = (rowL & 7) << 4;
  const int swb = (lr & 7) << 4;
  float4_t acc[8];
#pragma unroll
  for (int ct = 0; ct < 8; ++ct) acc[ct] = (float4_t){0.f, 0.f, 0.f, 0.f};
#pragma unroll
  for (int k0 = 0; k0 < 128; k0 += 32) {
    const int kb = 2 * k0 + hi * 8;
    uint2 alo = *(const uint2*)(Arow + (kb ^ swa));
    uint2 ahi2 = *(const uint2*)(Arow + ((kb + 32) ^ swa));
    Frag a; a.u = make_uint4(alo.x, alo.y, ahi2.x, ahi2.y);
#pragma unroll
    for (int ct = 0; ct < 8; ++ct) {
      const char* brow = wts + (ct * 16 + lr) * 256;
      uint2 blo = *(const uint2*)(brow + (kb ^ swb));
      uint2 bhi2 = *(const uint2*)(brow + ((kb + 32) ^ swb));
      Frag b; b.u = make_uint4(blo.x, blo.y, bhi2.x, bhi2.y);
      acc[ct] = __builtin_amdgcn_mfma_f32_16x16x32_f16(a.h, b.h, acc[ct], 0, 0, 0);
    }
  }
  int rr[4]; float dnv[4];
#pragma unroll
  for (int reg = 0; reg < 4; ++reg) {
    rr[reg] = row0 + wave * 16 + hi * 4 + reg;
    dnv[reg] = (rr[reg] < n) ? dinv[rr[reg]] : 0.f;
  }
#pragma unroll
  for (int ct = 0; ct < 8; ++ct) {
    int c = ct * 16 + lr;
#pragma unroll
    for (int reg = 0; reg < 4; ++reg)
      if (rr[reg] < n)
        outg[(size_t)rr[reg] * 128 + c] = __float2half(dnv[reg] * acc[ct][reg]);
  }
}

// gather128(g,+bias,relu) -> tile ; MFMA tile @ wt3 (128x16) -> outg 16ch
__global__ void __launch_bounds__(256) fgm16_kernel(
    const __half* __restrict__ g, const int2* __restrict__ csr, const float* __restrict__ dinv,
    const float* __restrict__ bias, const char* __restrict__ wt, __half* __restrict__ outg, int n) {
  __shared__ char wts[4096];
  __shared__ char tile[16384];
  if (threadIdx.x < 256) ((uint4*)wts)[threadIdx.x] = ((const uint4*)wt)[threadIdx.x];
  const int row0 = blockIdx.x * 64;
  gather_tile128(g, csr, dinv, bias, tile, row0, n);
  __syncthreads();

  const int wave = threadIdx.x >> 6, lane = threadIdx.x & 63;
  const int lr = lane & 15, hi = lane >> 4;
  const int rowL = wave * 16 + lr;
  const char* Arow = tile + rowL * 256;
  const int swa = (rowL & 7) << 4;
  const int swb = (lr & 7) << 4;
  const char* brow = wts + lr * 256;
  float4_t acc = (float4_t){0.f, 0.f, 0.f, 0.f};
#pragma unroll
  for (int k0 = 0; k0 < 128; k0 += 32) {
    const int kb = 2 * k0 + hi * 8;
    uint2 alo = *(const uint2*)(Arow + (kb ^ swa));
    uint2 ahi2 = *(const uint2*)(Arow + ((kb + 32) ^ swa));
    Frag a; a.u = make_uint4(alo.x, alo.y, ahi2.x, ahi2.y);
    uint2 blo = *(const uint2*)(brow + (kb ^ swb));
    uint2 bhi2 = *(const uint2*)(brow + ((kb + 32) ^ swb));
    Frag b; b.u = make_uint4(blo.x, blo.y, bhi2.x, bhi2.y);
    acc = __builtin_amdgcn_mfma_f32_16x16x32_f16(a.h, b.h, acc, 0, 0, 0);
  }
#pragma unroll
  for (int reg = 0; reg < 4; ++reg) {
    int r = row0 + wave * 16 + hi * 4 + reg;
    if (r < n) outg[(size_t)r * 16 + lr] = __float2half(dinv[r] * acc[reg]);
  }
}

// gather16(xs) -> a0 (fp32 LDS); x1 = relu(a0@w0+b0) -> x1s swizzled fp16; MFMA @wt1 -> g1
__global__ void __launch_bounds__(256) fused_l0l1_kernel(
    const __half* __restrict__ xs, const int2* __restrict__ csr, const float* __restrict__ dinv,
    const float* __restrict__ w0, const float* __restrict__ b0, const char* __restrict__ wt1,
    __half* __restrict__ g1, int n) {
  __shared__ float a0[64][17];
  __shared__ float ws0[16 * 128];
  __shared__ float bs0[128];
  __shared__ char wts[32768];
  __shared__ char x1s[16384];
  const int row0 = blockIdx.x * 64;
  for (int i = threadIdx.x; i < 2048; i += 256)
    ((uint4*)wts)[i] = ((const uint4*)wt1)[i];
  for (int i = threadIdx.x; i < 512; i += 256)
    ((float4*)ws0)[i] = ((const float4*)w0)[i];
  if (threadIdx.x < 128) bs0[threadIdx.x] = b0[threadIdx.x];

  // gather16 phase: 4 lanes/node, 64 nodes, fp32 accumulate -> a0
  {
    const int nd = threadIdx.x >> 2;
    const int c4 = threadIdx.x & 3;
    const int node = row0 + nd;
    float4 res = make_float4(0.f, 0.f, 0.f, 0.f);
    if (node < n) {
      const uint2* g2 = (const uint2*)xs;
      H2U2 self; self.u = g2[(size_t)node * 4 + c4];
      float2 s0 = __half22float2(self.h[0]), s1 = __half22float2(self.h[1]);
      float4 acc = make_float4(2.f * s0.x, 2.f * s0.y, 2.f * s1.x, 2.f * s1.y);
      const int2* row = csr + (size_t)node * RSTRIDE;
      const int cn = ((const int*)row)[0];
      int e = 0;
      for (; e + 4 <= cn; e += 4) {
        int2 ed[4];
#pragma unroll
        for (int j = 0; j < 4; ++j) ed[j] = row[1 + e + j];
        H2U2 v[4];
#pragma unroll
        for (int j = 0; j < 4; ++j) v[j].u = g2[(size_t)ed[j].x * 4 + c4];
#pragma unroll
        for (int j = 0; j < 4; ++j) {
          float w = __int_as_float(ed[j].y);
          float2 f0 = __half22float2(v[j].h[0]), f1 = __half22float2(v[j].h[1]);
          acc.x = fmaf(w, f0.x, acc.x); acc.y = fmaf(w, f0.y, acc.y);
          acc.z = fmaf(w, f1.x, acc.z); acc.w = fmaf(w, f1.y, acc.w);
        }
      }
      for (; e < cn; ++e) {
        int2 ed = row[1 + e];
        H2U2 v; v.u = g2[(size_t)ed.x * 4 + c4];
        float w = __int_as_float(ed.y);
        float2 f0 = __half22float2(v.h[0]), f1 = __half22float2(v.h[1]);
        acc.x = fmaf(w, f0.x, acc.x); acc.y = fmaf(w, f0.y, acc.y);
        acc.z = fmaf(w, f1.x, acc.z); acc.w = fmaf(w, f1.y, acc.w);
      }
      float dn = dinv[node];
      res = make_float4(dn * acc.x, dn * acc.y, dn * acc.z, dn * acc.w);
    }
    a0[nd][c4 * 4 + 0] = res.x; a0[nd][c4 * 4 + 1] = res.y;
    a0[nd][c4 * 4 + 2] = res.z; a0[nd][c4 * 4 + 3] = res.w;
  }
  __syncthreads();

  // GEMM1 (VALU): x1 = relu(a0 @ w0 + b0) -> x1s (swizzled fp16)
  {
    const int rg = threadIdx.x >> 4;
    const int c0 = (threadIdx.x & 15) << 3;
    float acc1[4][8];
#pragma unroll
    for (int i = 0; i < 4; ++i)
#pragma unroll
      for (int j = 0; j < 8; ++j) acc1[i][j] = bs0[c0 + j];
#pragma unroll
    for (int k = 0; k < 16; ++k) {
      float A0 = a0[rg * 4 + 0][k], A1 = a0[rg * 4 + 1][k];
      float A2 = a0[rg * 4 + 2][k], A3 = a0[rg * 4 + 3][k];
#pragma unroll
      for (int j = 0; j < 8; ++j) {
        float b = ws0[k * 128 + c0 + j];
        acc1[0][j] = fmaf(A0, b, acc1[0][j]);
        acc1[1][j] = fmaf(A1, b, acc1[1][j]);
        acc1[2][j] = fmaf(A2, b, acc1[2][j]);
        acc1[3][j] = fmaf(A3, b, acc1[3][j]);
      }
    }
#pragma unroll
    for (int i = 0; i < 4; ++i) {
      int row = rg * 4 + i;
      int swz = (row & 7) << 4;
#pragma unroll
      for (int jp = 0; jp < 4; ++jp) {
        int j = jp * 2;
        __half2 h = __float22half2_rn(make_float2(fmaxf(acc1[i][j], 0.f), fmaxf(acc1[i][j + 1], 0.f)));
        *(uint*)(x1s + row * 256 + ((2 * (c0 + j)) ^ swz)) = *(uint*)&h;
      }
    }
  }
  __syncthreads();

  // GEMM2 (MFMA): g1 = dinv .( x1 @ w1 )
  const int wave = threadIdx.x >> 6, lane = threadIdx.x & 63;
  const int lr = lane & 15, hi = lane >> 4;
  const int rowL = wave * 16 + lr;
  const char* Arow = x1s + rowL * 256;
  const int swa = (rowL & 7) << 4;
  const int swb = (lr & 7) << 4;
  float4_t acc[8];
#pragma unroll
  for (int ct = 0; ct < 8; ++ct) acc[ct] = (float4_t){0.f, 0.f, 0.f, 0.f};
#pragma unroll
  for (int k0 = 0; k0 < 128; k0 += 32) {
    const int kb = 2 * k0 + hi * 8;
    uint2 alo = *(const uint2*)(Arow + (kb ^ swa));
    uint2 ahi2 = *(const uint2*)(Arow + ((kb + 32) ^ swa));
    Frag a; a.u = make_uint4(alo.x, alo.y, ahi2.x, ahi2.y);
#pragma unroll
    for (int ct = 0; ct < 8; ++ct) {
      const char* brow = wts + (ct * 16 + lr) * 256;
      uint2 blo = *(const uint2*)(brow + (kb ^ swb));
      uint2 bhi2 = *(const uint2*)(brow + ((kb + 32) ^ swb));
      Frag b; b.u = make_uint4(blo.x, blo.y, bhi2.x, bhi2.y);
      acc[ct] = __builtin_amdgcn_mfma_f32_16x16x32_f16(a.h, b.h, acc[ct], 0, 0, 0);
    }
  }
  int rr[4]; float dnv[4];
#pragma unroll
  for (int reg = 0; reg < 4; ++reg) {
    rr[reg] = row0 + wave * 16 + hi * 4 + reg;
    dnv[reg] = (rr[reg] < n) ? dinv[rr[reg]] : 0.f;
  }
#pragma unroll
  for (int ct = 0; ct < 8; ++ct) {
    int c = ct * 16 + lr;
#pragma unroll
    for (int reg = 0; reg < 4; ++reg)
      if (rr[reg] < n)
        g1[(size_t)rr[reg] * 128 + c] = __float2half(dnv[reg] * acc[ct][reg]);
  }
}

// final gather: out fp32 = dinv*( sum w*g3[src] + 2*g3[n] ) + b3
__global__ void __launch_bounds__(256) gather16_final_kernel(
    const __half* __restrict__ g, const int2* __restrict__ csr, const float* __restrict__ dinv,
    const float* __restrict__ bias, float* __restrict__ dest, int n) {
  const int node = blockIdx.x * 64 + (threadIdx.x >> 2);
  const int cg = threadIdx.x & 3;
  if (node >= n) return;
  const uint2* g2 = (const uint2*)g;
  H2U2 self; self.u = g2[(size_t)node * 4 + cg];
  float2 s0 = __half22float2(self.h[0]), s1 = __half22float2(self.h[1]);
  float4 acc = make_float4(2.f * s0.x, 2.f * s0.y, 2.f * s1.x, 2.f * s1.y);
  const int2* row = csr + (size_t)node * RSTRIDE;
  const int cn = ((const int*)row)[0];
  int e = 0;
  for (; e + 4 <= cn; e += 4) {
    int2 ed[4];
#pragma unroll
    for (int j = 0; j < 4; ++j) ed[j] = row[1 + e + j];
    H2U2 v[4];
#pragma unroll
    for (int j = 0; j < 4; ++j) v[j].u = g2[(size_t)ed[j].x * 4 + cg];
#pragma unroll
    for (int j = 0; j < 4; ++j) {
      float w = __int_as_float(ed[j].y);
      float2 f0 = __half22float2(v[j].h[0]), f1 = __half22float2(v[j].h[1]);
      acc.x = fmaf(w, f0.x, acc.x); acc.y = fmaf(w, f0.y, acc.y);
      acc.z = fmaf(w, f1.x, acc.z); acc.w = fmaf(w, f1.y, acc.w);
    }
  }
  for (; e < cn; ++e) {
    int2 ed = row[1 + e];
    H2U2 v; v.u = g2[(size_t)ed.x * 4 + cg];
    float w = __int_as_float(ed.y);
    float2 f0 = __half22float2(v.h[0]), f1 = __half22float2(v.h[1]);
    acc.x = fmaf(w, f0.x, acc.x); acc.y = fmaf(w, f0.y, acc.y);
    acc.z = fmaf(w, f1.x, acc.z); acc.w = fmaf(w, f1.y, acc.w);
  }
  float dn = dinv[node];
  float4 bv = ((const float4*)bias)[cg];
  ((float4*)dest)[(size_t)node * 4 + cg] =
      make_float4(dn * acc.x + bv.x, dn * acc.y + bv.y, dn * acc.z + bv.z, dn * acc.w + bv.w);
}

// ---------------------------------------------------------------- launch

extern "C" void kernel_launch(void* const* d_in, const int* in_sizes, int n_in,
                              void* d_out, int out_size, void* d_ws, size_t ws_size,
                              hipStream_t stream) {
  const float* x  = (const float*)d_in[0];
  const int*   ei = (const int*)d_in[1];
  const float* ea = (const float*)d_in[2];
  const float* w0 = (const float*)d_in[3];
  const float* b0 = (const float*)d_in[4];
  const float* w1 = (const float*)d_in[5];
  const float* b1 = (const float*)d_in[6];
  const float* w2 = (const float*)d_in[7];
  const float* b2 = (const float*)d_in[8];
  const float* w3 = (const float*)d_in[9];
  const float* b3 = (const float*)d_in[10];
  float* out = (float*)d_out;

  const int* src = ei;       // edge_index[0]
  const int* dst = ei + NE;  // edge_index[1]

  // workspace: gA fp16 | gB fp16 | dinv | wt1 | wt2 | wt3 | csr  (~54.6 MB)
  __half* gA   = (__half*)d_ws;
  __half* gB   = gA + (size_t)NN * 128;
  float*  dinv = (float*)(gB + (size_t)NN * 128);
  char*   wt1  = (char*)(dinv + ((NN + 63) & ~63));
  char*   wt2  = wt1 + 32768;
  char*   wt3  = wt2 + 32768;
  int2*   csr  = (int2*)(wt3 + 4096);

  const int B = 256;
  auto blocks = [](long long t) { return (int)((t + 255) / 256); };
  const int gb64 = (NN + 63) / 64;  // 782

  prep_kernel<<<blocks(NN), B, 0, stream>>>(w1, w2, w3, wt1, wt2, wt3, csr);
  fill_pad_kernel<<<blocks(NE), B, 0, stream>>>(src, dst, ea, csr, NE);
  row_deg_xscale_kernel<<<blocks(NN), B, 0, stream>>>(csr, x, dinv, gA, NN);

  fused_l0l1_kernel<<<gb64, B, 0, stream>>>(gA, csr, dinv, w0, b0, wt1, gB, NN);
  fgm128_kernel<<<gb64, B, 0, stream>>>(gB, csr, dinv, b1, wt2, gA, NN);
  fgm16_kernel<<<gb64, B, 0, stream>>>(gA, csr, dinv, b2, wt3, gB, NN);
  gather16_final_kernel<<<blocks(NN * 4ll), B, 0, stream>>>(gB, csr, dinv, b3, out, NN);
}

// Round 11
// 185.078 us; speedup vs baseline: 1.0932x; 1.0932x over previous
//
#include <hip/hip_runtime.h>
#include <hip/hip_fp16.h>

// GCN, 4 layers, improved=True (self-loop weight 2.0), symmetric norm.
// N=50000 nodes, E=800000 edges, dims 16 -> 128 -> 128 -> 128 -> 16.
//
// R11: revert R10's gather+MFMA fusion (48KB LDS cut occupancy to 17% and
// starved the latency-bound gather of TLP). Back to R9's split pipeline,
// with a PACKED 4-byte CSR entry: src in low 16 bits (50000 < 2^16), ea as
// fp16 in high 16 bits. Row stride 320 B: cnt at word 0, entries 16B-aligned
// at words 4..67. Atomic-target set shrinks to 3.2 MB (L2-resident) and
// random-store line count halves -> fill_pad and all CSR reads get cheaper.
//
// Pipeline (10 kernels):
//   prep(zero cnt + wt fp16-swizzle) -> fill -> row_deg_xscale(gbuf=xs)
//   gather16<false>(gbuf)->Ah16 ; fused_l0l1(Ah16;w0,b0,wt1)->gbuf(g1)
//   gather128(+b1,relu)->Ah ; mfma128x128(Ah;wt2)->gbuf(g2)
//   gather128(+b2,relu)->Ah ; mfma128x16(Ah;wt3)->gbuf(g3)
//   gather16<true>(+b3)->out fp32

static constexpr int NN = 50000;
static constexpr int NE = 800000;
static constexpr int ROW_U = 80;  // uints per CSR row (320 B, 64B-aligned); cnt@0, entries@4..67

typedef _Float16 half8_t __attribute__((ext_vector_type(8)));
typedef float float4_t __attribute__((ext_vector_type(4)));

union Frag { uint4 u; half8_t h; };
union H2U2 { uint2 u; __half2 h[2]; };
union H4U4 { uint4 u; __half2 h[4]; };

__device__ __forceinline__ float unpack_w(uint e) {
  return __half2float(__ushort_as_half((ushort)(e >> 16)));
}

// ---------------------------------------------------------------- build

// zero csr counters + convert w1/w2/w3 to fp16 transposed [n][k] XOR-swizzled
__global__ void prep_kernel(const float* __restrict__ w1, const float* __restrict__ w2,
                            const float* __restrict__ w3, char* __restrict__ wt1,
                            char* __restrict__ wt2, char* __restrict__ wt3,
                            uint* __restrict__ csr) {
  int t = blockIdx.x * blockDim.x + threadIdx.x;
  if (t < NN) csr[(size_t)t * ROW_U] = 0u;
  if (t < 16384) {
    int k = t >> 7, n = t & 127;
    int off = n * 256 + ((2 * k) ^ ((n & 7) << 4));
    *(ushort*)(wt1 + off) = __half_as_ushort(__float2half(w1[t]));
    *(ushort*)(wt2 + off) = __half_as_ushort(__float2half(w2[t]));
  }
  if (t < 2048) {
    int k = t >> 4, n = t & 15;
    *(ushort*)(wt3 + n * 256 + ((2 * k) ^ ((n & 7) << 4))) = __half_as_ushort(__float2half(w3[t]));
  }
}

__global__ void fill_pad_kernel(const int* __restrict__ src, const int* __restrict__ dst,
                                const float* __restrict__ ea, uint* __restrict__ csr, int ne) {
  int i = blockIdx.x * blockDim.x + threadIdx.x;
  if (i < ne) {
    int d = dst[i];
    uint packed = ((uint)__half_as_ushort(__float2half(ea[i])) << 16) | (uint)src[i];
    int slot = atomicAdd((int*)(csr + (size_t)d * ROW_U), 1);
    csr[(size_t)d * ROW_U + 4 + slot] = packed;
  }
}

// dinv[i] = rsqrt(2 + sum row weights); xs[i][:] = dinv[i] * x[i][:] (fp16)
__global__ void row_deg_xscale_kernel(const uint* __restrict__ csr, const float* __restrict__ x,
                                      float* __restrict__ dinv, __half* __restrict__ xs, int n) {
  int i = blockIdx.x * blockDim.x + threadIdx.x;
  if (i >= n) return;
  const uint* row = csr + (size_t)i * ROW_U;
  const int cn = (int)row[0];
  float d = 2.0f;
  int e = 0;
  for (; e + 4 <= cn; e += 4) {
    uint4 q = *(const uint4*)(row + 4 + e);
    d += unpack_w(q.x) + unpack_w(q.y) + unpack_w(q.z) + unpack_w(q.w);
  }
  for (; e < cn; ++e) d += unpack_w(row[4 + e]);
  float dn = rsqrtf(d);  // d >= 2 always (ea >= 0)
  dinv[i] = dn;
  const float4* xr = (const float4*)(x + (size_t)i * 16);
  uint2* xo = (uint2*)(xs + (size_t)i * 16);
#pragma unroll
  for (int q = 0; q < 4; ++q) {
    float4 v = xr[q];
    H2U2 pk;
    pk.h[0] = __float22half2_rn(make_float2(dn * v.x, dn * v.y));
    pk.h[1] = __float22half2_rn(make_float2(dn * v.z, dn * v.w));
    xo[q] = pk.u;
  }
}

// ---------------------------------------------------------------- gathers

// C=16. FINAL: out fp32 +bias. else: out fp16, no bias (feeds fused GEMM).
template <bool FINAL>
__global__ void __launch_bounds__(256) gather16_kernel(
    const __half* __restrict__ g, const uint* __restrict__ csr, const float* __restrict__ dinv,
    const float* __restrict__ bias, void* __restrict__ dest, int n) {
  const int node = blockIdx.x * 64 + (threadIdx.x >> 2);
  const int cg = threadIdx.x & 3;  // 4 halfs (8 B) per lane
  if (node >= n) return;
  const uint2* g2 = (const uint2*)g;
  H2U2 self; self.u = g2[(size_t)node * 4 + cg];
  float2 s0 = __half22float2(self.h[0]), s1 = __half22float2(self.h[1]);
  float4 acc = make_float4(2.f * s0.x, 2.f * s0.y, 2.f * s1.x, 2.f * s1.y);

  const uint* row = csr + (size_t)node * ROW_U;
  const int cn = (int)row[0];
  int e = 0;
  for (; e + 4 <= cn; e += 4) {
    uint4 q = *(const uint4*)(row + 4 + e);
    uint ev[4] = {q.x, q.y, q.z, q.w};
    H2U2 v[4];
#pragma unroll
    for (int j = 0; j < 4; ++j) v[j].u = g2[(size_t)(ev[j] & 0xFFFFu) * 4 + cg];
#pragma unroll
    for (int j = 0; j < 4; ++j) {
      float w = unpack_w(ev[j]);
      float2 f0 = __half22float2(v[j].h[0]), f1 = __half22float2(v[j].h[1]);
      acc.x = fmaf(w, f0.x, acc.x); acc.y = fmaf(w, f0.y, acc.y);
      acc.z = fmaf(w, f1.x, acc.z); acc.w = fmaf(w, f1.y, acc.w);
    }
  }
  for (; e < cn; ++e) {
    uint ev = row[4 + e];
    H2U2 v; v.u = g2[(size_t)(ev & 0xFFFFu) * 4 + cg];
    float w = unpack_w(ev);
    float2 f0 = __half22float2(v.h[0]), f1 = __half22float2(v.h[1]);
    acc.x = fmaf(w, f0.x, acc.x); acc.y = fmaf(w, f0.y, acc.y);
    acc.z = fmaf(w, f1.x, acc.z); acc.w = fmaf(w, f1.y, acc.w);
  }
  float dn = dinv[node];
  if (FINAL) {
    float4 bv = ((const float4*)bias)[cg];
    ((float4*)dest)[(size_t)node * 4 + cg] =
        make_float4(dn * acc.x + bv.x, dn * acc.y + bv.y, dn * acc.z + bv.z, dn * acc.w + bv.w);
  } else {
    H2U2 pk;
    pk.h[0] = __float22half2_rn(make_float2(dn * acc.x, dn * acc.y));
    pk.h[1] = __float22half2_rn(make_float2(dn * acc.z, dn * acc.w));
    ((uint2*)dest)[(size_t)node * 4 + cg] = pk.u;
  }
}

// C=128, 16 lanes/node: out = relu(dinv*sum + bias) packed fp16 (MFMA input).
__global__ void __launch_bounds__(256) gather128_kernel(
    const __half* __restrict__ g, const uint* __restrict__ csr, const float* __restrict__ dinv,
    const float* __restrict__ bias, __half* __restrict__ aggh, int n) {
  const int node = blockIdx.x * 16 + (threadIdx.x >> 4);
  const int cg = threadIdx.x & 15;
  if (node >= n) return;
  const uint4* g4 = (const uint4*)g;  // row = 16 uint4
  float acc[8];
  {
    H4U4 self; self.u = g4[(size_t)node * 16 + cg];
    float2 f0 = __half22float2(self.h[0]), f1 = __half22float2(self.h[1]);
    float2 f2 = __half22float2(self.h[2]), f3 = __half22float2(self.h[3]);
    acc[0] = 2.f * f0.x; acc[1] = 2.f * f0.y; acc[2] = 2.f * f1.x; acc[3] = 2.f * f1.y;
    acc[4] = 2.f * f2.x; acc[5] = 2.f * f2.y; acc[6] = 2.f * f3.x; acc[7] = 2.f * f3.y;
  }
  const uint* row = csr + (size_t)node * ROW_U;
  const int cn = (int)row[0];
  int e = 0;
  for (; e + 4 <= cn; e += 4) {
    uint4 q = *(const uint4*)(row + 4 + e);
    uint ev[4] = {q.x, q.y, q.z, q.w};
    H4U4 v[4];
#pragma unroll
    for (int j = 0; j < 4; ++j) v[j].u = g4[(size_t)(ev[j] & 0xFFFFu) * 16 + cg];
#pragma unroll
    for (int j = 0; j < 4; ++j) {
      float w = unpack_w(ev[j]);
      float2 f0 = __half22float2(v[j].h[0]), f1 = __half22float2(v[j].h[1]);
      float2 f2 = __half22float2(v[j].h[2]), f3 = __half22float2(v[j].h[3]);
      acc[0] = fmaf(w, f0.x, acc[0]); acc[1] = fmaf(w, f0.y, acc[1]);
      acc[2] = fmaf(w, f1.x, acc[2]); acc[3] = fmaf(w, f1.y, acc[3]);
      acc[4] = fmaf(w, f2.x, acc[4]); acc[5] = fmaf(w, f2.y, acc[5]);
      acc[6] = fmaf(w, f3.x, acc[6]); acc[7] = fmaf(w, f3.y, acc[7]);
    }
  }
  for (; e < cn; ++e) {
    uint ev = row[4 + e];
    H4U4 v; v.u = g4[(size_t)(ev & 0xFFFFu) * 16 + cg];
    float w = unpack_w(ev);
    float2 f0 = __half22float2(v.h[0]), f1 = __half22float2(v.h[1]);
    float2 f2 = __half22float2(v.h[2]), f3 = __half22float2(v.h[3]);
    acc[0] = fmaf(w, f0.x, acc[0]); acc[1] = fmaf(w, f0.y, acc[1]);
    acc[2] = fmaf(w, f1.x, acc[2]); acc[3] = fmaf(w, f1.y, acc[3]);
    acc[4] = fmaf(w, f2.x, acc[4]); acc[5] = fmaf(w, f2.y, acc[5]);
    acc[6] = fmaf(w, f3.x, acc[6]); acc[7] = fmaf(w, f3.y, acc[7]);
  }
  const float dn = dinv[node];
  const float4* b4 = (const float4*)bias;
  float4 bl = b4[cg * 2], bh = b4[cg * 2 + 1];
  float r[8];
  r[0] = fmaxf(dn * acc[0] + bl.x, 0.f); r[1] = fmaxf(dn * acc[1] + bl.y, 0.f);
  r[2] = fmaxf(dn * acc[2] + bl.z, 0.f); r[3] = fmaxf(dn * acc[3] + bl.w, 0.f);
  r[4] = fmaxf(dn * acc[4] + bh.x, 0.f); r[5] = fmaxf(dn * acc[5] + bh.y, 0.f);
  r[6] = fmaxf(dn * acc[6] + bh.z, 0.f); r[7] = fmaxf(dn * acc[7] + bh.w, 0.f);
  H4U4 pk;
  pk.h[0] = __float22half2_rn(make_float2(r[0], r[1]));
  pk.h[1] = __float22half2_rn(make_float2(r[2], r[3]));
  pk.h[2] = __float22half2_rn(make_float2(r[4], r[5]));
  pk.h[3] = __float22half2_rn(make_float2(r[6], r[7]));
  ((uint4*)aggh)[(size_t)node * 16 + cg] = pk.u;
}

// ---------------------------------------------------------------- MFMA GEMMs

// g2 = dinv .( Ah @ w2 ),  Ah fp16 [n][128] (already relu'd), wt pre-swizzled.
__global__ void __launch_bounds__(256) mfma128x128_kernel(
    const __half* __restrict__ Ah, const char* __restrict__ wt,
    const float* __restrict__ dinv, __half* __restrict__ outg, int n) {
  __shared__ char wts[32768];
  for (int i = threadIdx.x; i < 2048; i += 256)
    ((uint4*)wts)[i] = ((const uint4*)wt)[i];
  __syncthreads();
  const int row0 = blockIdx.x * 64;
  const int wave = threadIdx.x >> 6, lane = threadIdx.x & 63;
  const int lr = lane & 15, hi = lane >> 4;
  const int rowL = wave * 16 + lr;
  const char* Arow = (const char*)(Ah + (size_t)(row0 + rowL) * 128);
  const int sw = (lr & 7) << 4;
  float4_t acc[8];
#pragma unroll
  for (int ct = 0; ct < 8; ++ct) acc[ct] = (float4_t){0.f, 0.f, 0.f, 0.f};
#pragma unroll
  for (int k0 = 0; k0 < 128; k0 += 32) {
    const int kb = 2 * k0 + hi * 8;
    uint2 alo = *(const uint2*)(Arow + kb);
    uint2 ahi2 = *(const uint2*)(Arow + kb + 32);
    Frag a; a.u = make_uint4(alo.x, alo.y, ahi2.x, ahi2.y);
#pragma unroll
    for (int ct = 0; ct < 8; ++ct) {
      const char* brow = wts + (ct * 16 + lr) * 256;
      uint2 blo = *(const uint2*)(brow + (kb ^ sw));
      uint2 bhi2 = *(const uint2*)(brow + ((kb + 32) ^ sw));
      Frag b; b.u = make_uint4(blo.x, blo.y, bhi2.x, bhi2.y);
      acc[ct] = __builtin_amdgcn_mfma_f32_16x16x32_f16(a.h, b.h, acc[ct], 0, 0, 0);
    }
  }
  int rr[4]; float dnv[4];
#pragma unroll
  for (int reg = 0; reg < 4; ++reg) {
    rr[reg] = row0 + wave * 16 + hi * 4 + reg;
    dnv[reg] = (rr[reg] < n) ? dinv[rr[reg]] : 0.f;
  }
#pragma unroll
  for (int ct = 0; ct < 8; ++ct) {
    int c = ct * 16 + lr;
#pragma unroll
    for (int reg = 0; reg < 4; ++reg)
      if (rr[reg] < n)
        outg[(size_t)rr[reg] * 128 + c] = __float2half(dnv[reg] * acc[ct][reg]);
  }
}

// g3 = dinv .( Ah @ w3 ), 128 -> 16.
__global__ void __launch_bounds__(256) mfma128x16_kernel(
    const __half* __restrict__ Ah, const char* __restrict__ wt,
    const float* __restrict__ dinv, __half* __restrict__ outg, int n) {
  __shared__ char wts[4096];
  if (threadIdx.x < 256) ((uint4*)wts)[threadIdx.x] = ((const uint4*)wt)[threadIdx.x];
  __syncthreads();
  const int row0 = blockIdx.x * 64;
  const int wave = threadIdx.x >> 6, lane = threadIdx.x & 63;
  const int lr = lane & 15, hi = lane >> 4;
  const int rowL = wave * 16 + lr;
  const char* Arow = (const char*)(Ah + (size_t)(row0 + rowL) * 128);
  const int sw = (lr & 7) << 4;
  const char* brow = wts + lr * 256;
  float4_t acc = (float4_t){0.f, 0.f, 0.f, 0.f};
#pragma unroll
  for (int k0 = 0; k0 < 128; k0 += 32) {
    const int kb = 2 * k0 + hi * 8;
    uint2 alo = *(const uint2*)(Arow + kb);
    uint2 ahi2 = *(const uint2*)(Arow + kb + 32);
    Frag a; a.u = make_uint4(alo.x, alo.y, ahi2.x, ahi2.y);
    uint2 blo = *(const uint2*)(brow + (kb ^ sw));
    uint2 bhi2 = *(const uint2*)(brow + ((kb + 32) ^ sw));
    Frag b; b.u = make_uint4(blo.x, blo.y, bhi2.x, bhi2.y);
    acc = __builtin_amdgcn_mfma_f32_16x16x32_f16(a.h, b.h, acc, 0, 0, 0);
  }
#pragma unroll
  for (int reg = 0; reg < 4; ++reg) {
    int r = row0 + wave * 16 + hi * 4 + reg;
    if (r < n) outg[(size_t)r * 16 + lr] = __float2half(dinv[r] * acc[reg]);
  }
}

// fused layer-0: x1 = relu(A16h@w0 + b0) (VALU, K=16) -> swizzled fp16 LDS;
// g1 = dinv .( x1 @ w1 ) via MFMA.
__global__ void __launch_bounds__(256) fused_l0l1_kernel(
    const __half* __restrict__ A16h, const float* __restrict__ w0, const float* __restrict__ b0,
    const char* __restrict__ wt1, const float* __restrict__ dinv, __half* __restrict__ g1, int n) {
  __shared__ float a0[64][17];
  __shared__ float ws0[16 * 128];
  __shared__ float bs0[128];
  __shared__ char wts[32768];
  __shared__ char x1s[16384];
  const int row0 = blockIdx.x * 64;
  for (int i = threadIdx.x; i < 2048; i += 256)
    ((uint4*)wts)[i] = ((const uint4*)wt1)[i];
  for (int i = threadIdx.x; i < 512; i += 256)
    ((float4*)ws0)[i] = ((const float4*)w0)[i];
  if (threadIdx.x < 128) bs0[threadIdx.x] = b0[threadIdx.x];
  {
    int r = threadIdx.x >> 2, c8 = threadIdx.x & 3;
    H2U2 v; v.u = make_uint2(0u, 0u);
    if (row0 + r < n) v.u = ((const uint2*)(A16h + (size_t)(row0 + r) * 16))[c8];
    float2 f0 = __half22float2(v.h[0]), f1 = __half22float2(v.h[1]);
    a0[r][c8 * 4 + 0] = f0.x; a0[r][c8 * 4 + 1] = f0.y;
    a0[r][c8 * 4 + 2] = f1.x; a0[r][c8 * 4 + 3] = f1.y;
  }
  __syncthreads();

  // GEMM1 (VALU): x1 = relu(a0 @ w0 + b0) -> x1s (swizzled fp16)
  {
    const int rg = threadIdx.x >> 4;
    const int c0 = (threadIdx.x & 15) << 3;
    float acc1[4][8];
#pragma unroll
    for (int i = 0; i < 4; ++i)
#pragma unroll
      for (int j = 0; j < 8; ++j) acc1[i][j] = bs0[c0 + j];
#pragma unroll
    for (int k = 0; k < 16; ++k) {
      float A0 = a0[rg * 4 + 0][k], A1 = a0[rg * 4 + 1][k];
      float A2 = a0[rg * 4 + 2][k], A3 = a0[rg * 4 + 3][k];
#pragma unroll
      for (int j = 0; j < 8; ++j) {
        float b = ws0[k * 128 + c0 + j];
        acc1[0][j] = fmaf(A0, b, acc1[0][j]);
        acc1[1][j] = fmaf(A1, b, acc1[1][j]);
        acc1[2][j] = fmaf(A2, b, acc1[2][j]);
        acc1[3][j] = fmaf(A3, b, acc1[3][j]);
      }
    }
#pragma unroll
    for (int i = 0; i < 4; ++i) {
      int row = rg * 4 + i;
      int swz = (row & 7) << 4;
#pragma unroll
      for (int jp = 0; jp < 4; ++jp) {
        int j = jp * 2;
        __half2 h = __float22half2_rn(make_float2(fmaxf(acc1[i][j], 0.f), fmaxf(acc1[i][j + 1], 0.f)));
        *(uint*)(x1s + row * 256 + ((2 * (c0 + j)) ^ swz)) = *(uint*)&h;
      }
    }
  }
  __syncthreads();

  // GEMM2 (MFMA): g1 = dinv .( x1 @ w1 )
  const int wave = threadIdx.x >> 6, lane = threadIdx.x & 63;
  const int lr = lane & 15, hi = lane >> 4;
  const int rowL = wave * 16 + lr;
  const char* Arow = x1s + rowL * 256;
  const int swa = (rowL & 7) << 4;
  const int swb = (lr & 7) << 4;
  float4_t acc[8];
#pragma unroll
  for (int ct = 0; ct < 8; ++ct) acc[ct] = (float4_t){0.f, 0.f, 0.f, 0.f};
#pragma unroll
  for (int k0 = 0; k0 < 128; k0 += 32) {
    const int kb = 2 * k0 + hi * 8;
    uint2 alo = *(const uint2*)(Arow + (kb ^ swa));
    uint2 ahi2 = *(const uint2*)(Arow + ((kb + 32) ^ swa));
    Frag a; a.u = make_uint4(alo.x, alo.y, ahi2.x, ahi2.y);
#pragma unroll
    for (int ct = 0; ct < 8; ++ct) {
      const char* brow = wts + (ct * 16 + lr) * 256;
      uint2 blo = *(const uint2*)(brow + (kb ^ swb));
      uint2 bhi2 = *(const uint2*)(brow + ((kb + 32) ^ swb));
      Frag b; b.u = make_uint4(blo.x, blo.y, bhi2.x, bhi2.y);
      acc[ct] = __builtin_amdgcn_mfma_f32_16x16x32_f16(a.h, b.h, acc[ct], 0, 0, 0);
    }
  }
  int rr[4]; float dnv[4];
#pragma unroll
  for (int reg = 0; reg < 4; ++reg) {
    rr[reg] = row0 + wave * 16 + hi * 4 + reg;
    dnv[reg] = (rr[reg] < n) ? dinv[rr[reg]] : 0.f;
  }
#pragma unroll
  for (int ct = 0; ct < 8; ++ct) {
    int c = ct * 16 + lr;
#pragma unroll
    for (int reg = 0; reg < 4; ++reg)
      if (rr[reg] < n)
        g1[(size_t)rr[reg] * 128 + c] = __float2half(dnv[reg] * acc[ct][reg]);
  }
}

// ---------------------------------------------------------------- launch

extern "C" void kernel_launch(void* const* d_in, const int* in_sizes, int n_in,
                              void* d_out, int out_size, void* d_ws, size_t ws_size,
                              hipStream_t stream) {
  const float* x  = (const float*)d_in[0];
  const int*   ei = (const int*)d_in[1];
  const float* ea = (const float*)d_in[2];
  const float* w0 = (const float*)d_in[3];
  const float* b0 = (const float*)d_in[4];
  const float* w1 = (const float*)d_in[5];
  const float* b1 = (const float*)d_in[6];
  const float* w2 = (const float*)d_in[7];
  const float* b2 = (const float*)d_in[8];
  const float* w3 = (const float*)d_in[9];
  const float* b3 = (const float*)d_in[10];
  float* out = (float*)d_out;

  const int* src = ei;       // edge_index[0]
  const int* dst = ei + NE;  // edge_index[1]

  // workspace: Ah fp16 | gbuf fp16 | dinv | wt1 | wt2 | wt3 | csr(uint, 16MB)  (~42 MB)
  __half* Ah   = (__half*)d_ws;
  __half* gbuf = Ah + (size_t)NN * 128;
  float*  dinv = (float*)(gbuf + (size_t)NN * 128);
  char*   wt1  = (char*)(dinv + ((NN + 63) & ~63));
  char*   wt2  = wt1 + 32768;
  char*   wt3  = wt2 + 32768;
  uint*   csr  = (uint*)(wt3 + 4096);

  const int B = 256;
  auto blocks = [](long long t) { return (int)((t + 255) / 256); };
  const int gb64 = (NN + 63) / 64;  // 782

  // build
  prep_kernel<<<blocks(NN), B, 0, stream>>>(w1, w2, w3, wt1, wt2, wt3, csr);
  fill_pad_kernel<<<blocks(NE), B, 0, stream>>>(src, dst, ea, csr, NE);
  row_deg_xscale_kernel<<<blocks(NN), B, 0, stream>>>(csr, x, dinv, gbuf, NN);

  // layer 0: gather xs(16ch fp16) -> Ah16, fused -> g1 fp16
  gather16_kernel<false><<<(NN + 63) / 64, B, 0, stream>>>(gbuf, csr, dinv, nullptr, Ah, NN);
  fused_l0l1_kernel<<<gb64, B, 0, stream>>>(Ah, w0, b0, wt1, dinv, gbuf, NN);

  // layer 1: gather g1 (+b1, relu) -> Ah fp16 ; MFMA @w2 -> g2
  gather128_kernel<<<(NN + 15) / 16, B, 0, stream>>>(gbuf, csr, dinv, b1, Ah, NN);
  mfma128x128_kernel<<<gb64, B, 0, stream>>>(Ah, wt2, dinv, gbuf, NN);

  // layer 2: gather g2 (+b2, relu) -> Ah ; MFMA @w3 -> g3 (16ch)
  gather128_kernel<<<(NN + 15) / 16, B, 0, stream>>>(gbuf, csr, dinv, b2, Ah, NN);
  mfma128x16_kernel<<<gb64, B, 0, stream>>>(Ah, wt3, dinv, gbuf, NN);

  // layer 3: final gather (+b3) -> out fp32
  gather16_kernel<true><<<(NN + 63) / 64, B, 0, stream>>>(gbuf, csr, dinv, b3, out, NN);
}

// Round 12
// 173.839 us; speedup vs baseline: 1.1639x; 1.0647x over previous
//
#include <hip/hip_runtime.h>
#include <hip/hip_fp16.h>

// GCN, 4 layers, improved=True (self-loop weight 2.0), symmetric norm.
// N=50000 nodes, E=800000 edges, dims 16 -> 128 -> 128 -> 128 -> 16.
//
// R12: atomic-free CSR build via bucket sort (the per-edge device-scope
// atomicAdd hit the ~17 G RMW/s fabric ceiling; 64B writeback per atomic).
//   hist:   per-block LDS histogram of dst>>6 (782 buckets)
//   bscan:  per-bucket exclusive scan over the 196 block counts (in-place)
//   scat:   rank via LDS atomic, write {dst, ea16|src16} to padded bucket
//   build:  per-bucket (64 dsts): LDS count/deg/slot -> padded CSR rows
//           (ROW_U=80, identical layout to R11) + dinv + fused xscale
// Gather / MFMA kernels unchanged from R11 (packed 4B CSR entries).

static constexpr int NN = 50000;
static constexpr int NE = 800000;
static constexpr int ROW_U = 80;  // uints per CSR row; cnt@0, entries@4..79
static constexpr int NBKT = (NN + 63) / 64;        // 782 coarse buckets
static constexpr int BCAP = 1280;                  // padded bucket capacity (mean 1023 + 8 sigma)
static constexpr int EPB = 4096;                   // edges per hist/scatter block
static constexpr int NBLK = (NE + EPB - 1) / EPB;  // 196

typedef _Float16 half8_t __attribute__((ext_vector_type(8)));
typedef float float4_t __attribute__((ext_vector_type(4)));

union Frag { uint4 u; half8_t h; };
union H2U2 { uint2 u; __half2 h[2]; };
union H4U4 { uint4 u; __half2 h[4]; };

__device__ __forceinline__ float unpack_w(uint e) {
  return __half2float(__ushort_as_half((ushort)(e >> 16)));
}

// ---------------------------------------------------------------- build

// convert w1/w2/w3 to fp16 transposed [n][k] XOR-swizzled
__global__ void prep_kernel(const float* __restrict__ w1, const float* __restrict__ w2,
                            const float* __restrict__ w3, char* __restrict__ wt1,
                            char* __restrict__ wt2, char* __restrict__ wt3) {
  int t = blockIdx.x * blockDim.x + threadIdx.x;
  if (t < 16384) {
    int k = t >> 7, n = t & 127;
    int off = n * 256 + ((2 * k) ^ ((n & 7) << 4));
    *(ushort*)(wt1 + off) = __half_as_ushort(__float2half(w1[t]));
    *(ushort*)(wt2 + off) = __half_as_ushort(__float2half(w2[t]));
  }
  if (t < 2048) {
    int k = t >> 4, n = t & 15;
    *(ushort*)(wt3 + n * 256 + ((2 * k) ^ ((n & 7) << 4))) = __half_as_ushort(__float2half(w3[t]));
  }
}

// pass 1: per-block bucket histogram
__global__ void __launch_bounds__(256) hist_kernel(const int* __restrict__ dst,
                                                   int* __restrict__ blockhist, int ne) {
  __shared__ int bin[NBKT];
  const int b = blockIdx.x, t = threadIdx.x;
  for (int k = t; k < NBKT; k += 256) bin[k] = 0;
  __syncthreads();
  const int e0 = b * EPB, e1 = min(e0 + EPB, ne);
  for (int i = e0 + t; i < e1; i += 256) atomicAdd(&bin[dst[i] >> 6], 1);
  __syncthreads();
  for (int k = t; k < NBKT; k += 256) blockhist[(size_t)k * NBLK + b] = bin[k];
}

// pass 2: exclusive scan of each bucket's block counts (in-place) + totals
__global__ void __launch_bounds__(256) bscan_kernel(int* __restrict__ blockhist,
                                                    int* __restrict__ bucket_total) {
  __shared__ int s[256];
  const int bkt = blockIdx.x, t = threadIdx.x;
  int v = (t < NBLK) ? blockhist[(size_t)bkt * NBLK + t] : 0;
  s[t] = v;
  __syncthreads();
  for (int off = 1; off < 256; off <<= 1) {
    int u = (t >= off) ? s[t - off] : 0;
    __syncthreads();
    s[t] += u;
    __syncthreads();
  }
  if (t < NBLK) blockhist[(size_t)bkt * NBLK + t] = s[t] - v;  // exclusive
  if (t == 255) bucket_total[bkt] = s[255];
}

// pass 3: scatter edges into bucket-sorted buffer (rank via LDS atomic)
__global__ void __launch_bounds__(256) scat_kernel(
    const int* __restrict__ src, const int* __restrict__ dst, const float* __restrict__ ea,
    const int* __restrict__ blockbase, uint2* __restrict__ sorted, int ne) {
  __shared__ int lbase[NBKT];
  __shared__ int lbin[NBKT];
  const int b = blockIdx.x, t = threadIdx.x;
  for (int k = t; k < NBKT; k += 256) {
    lbase[k] = blockbase[(size_t)k * NBLK + b];
    lbin[k] = 0;
  }
  __syncthreads();
  const int e0 = b * EPB, e1 = min(e0 + EPB, ne);
  for (int i = e0 + t; i < e1; i += 256) {
    const int d = dst[i];
    const int bkt = d >> 6;
    const int r = atomicAdd(&lbin[bkt], 1);
    const uint entry = ((uint)__half_as_ushort(__float2half(ea[i])) << 16) | (uint)src[i];
    sorted[(size_t)bkt * BCAP + lbase[bkt] + r] = make_uint2((uint)d, entry);
  }
}

// pass 4: per-bucket CSR rows + dinv + xscale (bucket = 64 consecutive dsts)
__global__ void __launch_bounds__(256) build_kernel(
    const uint2* __restrict__ sorted, const int* __restrict__ bucket_total,
    const float* __restrict__ x, uint* __restrict__ csr, float* __restrict__ dinv,
    __half* __restrict__ xs, int n) {
  __shared__ int lcnt[64], lpos[64];
  __shared__ float ldeg[64], ldinv[64];
  const int bkt = blockIdx.x, t = threadIdx.x;
  if (t < 64) { lcnt[t] = 0; lpos[t] = 0; ldeg[t] = 0.f; }
  __syncthreads();
  const int d0 = bkt * 64;
  const int cn = bucket_total[bkt];
  const uint2* base = sorted + (size_t)bkt * BCAP;
  for (int i = t; i < cn; i += 256) {
    uint2 e = base[i];
    int ld = (int)e.x - d0;
    atomicAdd(&lcnt[ld], 1);
    atomicAdd(&ldeg[ld], unpack_w(e.y));
  }
  __syncthreads();
  if (t < 64 && d0 + t < n) {
    csr[(size_t)(d0 + t) * ROW_U] = (uint)lcnt[t];
    float dn = rsqrtf(2.f + ldeg[t]);  // deg >= 2 always (ea >= 0)
    ldinv[t] = dn;
    dinv[d0 + t] = dn;
  }
  __syncthreads();
  for (int i = t; i < cn; i += 256) {
    uint2 e = base[i];
    int ld = (int)e.x - d0;
    int slot = atomicAdd(&lpos[ld], 1);
    csr[(size_t)e.x * ROW_U + 4 + slot] = e.y;
  }
  // fused xscale: this bucket's 64 nodes, 4 lanes each
  {
    const int nd = t >> 2, c4 = t & 3;
    const int node = d0 + nd;
    if (node < n) {
      float dn = ldinv[nd];
      float4 v = ((const float4*)(x + (size_t)node * 16))[c4];
      H2U2 pk;
      pk.h[0] = __float22half2_rn(make_float2(dn * v.x, dn * v.y));
      pk.h[1] = __float22half2_rn(make_float2(dn * v.z, dn * v.w));
      ((uint2*)(xs + (size_t)node * 16))[c4] = pk.u;
    }
  }
}

// ---------------------------------------------------------------- gathers (R11, unchanged)

template <bool FINAL>
__global__ void __launch_bounds__(256) gather16_kernel(
    const __half* __restrict__ g, const uint* __restrict__ csr, const float* __restrict__ dinv,
    const float* __restrict__ bias, void* __restrict__ dest, int n) {
  const int node = blockIdx.x * 64 + (threadIdx.x >> 2);
  const int cg = threadIdx.x & 3;
  if (node >= n) return;
  const uint2* g2 = (const uint2*)g;
  H2U2 self; self.u = g2[(size_t)node * 4 + cg];
  float2 s0 = __half22float2(self.h[0]), s1 = __half22float2(self.h[1]);
  float4 acc = make_float4(2.f * s0.x, 2.f * s0.y, 2.f * s1.x, 2.f * s1.y);

  const uint* row = csr + (size_t)node * ROW_U;
  const int cn = (int)row[0];
  int e = 0;
  for (; e + 4 <= cn; e += 4) {
    uint4 q = *(const uint4*)(row + 4 + e);
    uint ev[4] = {q.x, q.y, q.z, q.w};
    H2U2 v[4];
#pragma unroll
    for (int j = 0; j < 4; ++j) v[j].u = g2[(size_t)(ev[j] & 0xFFFFu) * 4 + cg];
#pragma unroll
    for (int j = 0; j < 4; ++j) {
      float w = unpack_w(ev[j]);
      float2 f0 = __half22float2(v[j].h[0]), f1 = __half22float2(v[j].h[1]);
      acc.x = fmaf(w, f0.x, acc.x); acc.y = fmaf(w, f0.y, acc.y);
      acc.z = fmaf(w, f1.x, acc.z); acc.w = fmaf(w, f1.y, acc.w);
    }
  }
  for (; e < cn; ++e) {
    uint ev = row[4 + e];
    H2U2 v; v.u = g2[(size_t)(ev & 0xFFFFu) * 4 + cg];
    float w = unpack_w(ev);
    float2 f0 = __half22float2(v.h[0]), f1 = __half22float2(v.h[1]);
    acc.x = fmaf(w, f0.x, acc.x); acc.y = fmaf(w, f0.y, acc.y);
    acc.z = fmaf(w, f1.x, acc.z); acc.w = fmaf(w, f1.y, acc.w);
  }
  float dn = dinv[node];
  if (FINAL) {
    float4 bv = ((const float4*)bias)[cg];
    ((float4*)dest)[(size_t)node * 4 + cg] =
        make_float4(dn * acc.x + bv.x, dn * acc.y + bv.y, dn * acc.z + bv.z, dn * acc.w + bv.w);
  } else {
    H2U2 pk;
    pk.h[0] = __float22half2_rn(make_float2(dn * acc.x, dn * acc.y));
    pk.h[1] = __float22half2_rn(make_float2(dn * acc.z, dn * acc.w));
    ((uint2*)dest)[(size_t)node * 4 + cg] = pk.u;
  }
}

__global__ void __launch_bounds__(256) gather128_kernel(
    const __half* __restrict__ g, const uint* __restrict__ csr, const float* __restrict__ dinv,
    const float* __restrict__ bias, __half* __restrict__ aggh, int n) {
  const int node = blockIdx.x * 16 + (threadIdx.x >> 4);
  const int cg = threadIdx.x & 15;
  if (node >= n) return;
  const uint4* g4 = (const uint4*)g;
  float acc[8];
  {
    H4U4 self; self.u = g4[(size_t)node * 16 + cg];
    float2 f0 = __half22float2(self.h[0]), f1 = __half22float2(self.h[1]);
    float2 f2 = __half22float2(self.h[2]), f3 = __half22float2(self.h[3]);
    acc[0] = 2.f * f0.x; acc[1] = 2.f * f0.y; acc[2] = 2.f * f1.x; acc[3] = 2.f * f1.y;
    acc[4] = 2.f * f2.x; acc[5] = 2.f * f2.y; acc[6] = 2.f * f3.x; acc[7] = 2.f * f3.y;
  }
  const uint* row = csr + (size_t)node * ROW_U;
  const int cn = (int)row[0];
  int e = 0;
  for (; e + 4 <= cn; e += 4) {
    uint4 q = *(const uint4*)(row + 4 + e);
    uint ev[4] = {q.x, q.y, q.z, q.w};
    H4U4 v[4];
#pragma unroll
    for (int j = 0; j < 4; ++j) v[j].u = g4[(size_t)(ev[j] & 0xFFFFu) * 16 + cg];
#pragma unroll
    for (int j = 0; j < 4; ++j) {
      float w = unpack_w(ev[j]);
      float2 f0 = __half22float2(v[j].h[0]), f1 = __half22float2(v[j].h[1]);
      float2 f2 = __half22float2(v[j].h[2]), f3 = __half22float2(v[j].h[3]);
      acc[0] = fmaf(w, f0.x, acc[0]); acc[1] = fmaf(w, f0.y, acc[1]);
      acc[2] = fmaf(w, f1.x, acc[2]); acc[3] = fmaf(w, f1.y, acc[3]);
      acc[4] = fmaf(w, f2.x, acc[4]); acc[5] = fmaf(w, f2.y, acc[5]);
      acc[6] = fmaf(w, f3.x, acc[6]); acc[7] = fmaf(w, f3.y, acc[7]);
    }
  }
  for (; e < cn; ++e) {
    uint ev = row[4 + e];
    H4U4 v; v.u = g4[(size_t)(ev & 0xFFFFu) * 16 + cg];
    float w = unpack_w(ev);
    float2 f0 = __half22float2(v.h[0]), f1 = __half22float2(v.h[1]);
    float2 f2 = __half22float2(v.h[2]), f3 = __half22float2(v.h[3]);
    acc[0] = fmaf(w, f0.x, acc[0]); acc[1] = fmaf(w, f0.y, acc[1]);
    acc[2] = fmaf(w, f1.x, acc[2]); acc[3] = fmaf(w, f1.y, acc[3]);
    acc[4] = fmaf(w, f2.x, acc[4]); acc[5] = fmaf(w, f2.y, acc[5]);
    acc[6] = fmaf(w, f3.x, acc[6]); acc[7] = fmaf(w, f3.y, acc[7]);
  }
  const float dn = dinv[node];
  const float4* b4 = (const float4*)bias;
  float4 bl = b4[cg * 2], bh = b4[cg * 2 + 1];
  float r[8];
  r[0] = fmaxf(dn * acc[0] + bl.x, 0.f); r[1] = fmaxf(dn * acc[1] + bl.y, 0.f);
  r[2] = fmaxf(dn * acc[2] + bl.z, 0.f); r[3] = fmaxf(dn * acc[3] + bl.w, 0.f);
  r[4] = fmaxf(dn * acc[4] + bh.x, 0.f); r[5] = fmaxf(dn * acc[5] + bh.y, 0.f);
  r[6] = fmaxf(dn * acc[6] + bh.z, 0.f); r[7] = fmaxf(dn * acc[7] + bh.w, 0.f);
  H4U4 pk;
  pk.h[0] = __float22half2_rn(make_float2(r[0], r[1]));
  pk.h[1] = __float22half2_rn(make_float2(r[2], r[3]));
  pk.h[2] = __float22half2_rn(make_float2(r[4], r[5]));
  pk.h[3] = __float22half2_rn(make_float2(r[6], r[7]));
  ((uint4*)aggh)[(size_t)node * 16 + cg] = pk.u;
}

// ---------------------------------------------------------------- MFMA GEMMs (R11, unchanged)

__global__ void __launch_bounds__(256) mfma128x128_kernel(
    const __half* __restrict__ Ah, const char* __restrict__ wt,
    const float* __restrict__ dinv, __half* __restrict__ outg, int n) {
  __shared__ char wts[32768];
  for (int i = threadIdx.x; i < 2048; i += 256)
    ((uint4*)wts)[i] = ((const uint4*)wt)[i];
  __syncthreads();
  const int row0 = blockIdx.x * 64;
  const int wave = threadIdx.x >> 6, lane = threadIdx.x & 63;
  const int lr = lane & 15, hi = lane >> 4;
  const int rowL = wave * 16 + lr;
  const char* Arow = (const char*)(Ah + (size_t)(row0 + rowL) * 128);
  const int sw = (lr & 7) << 4;
  float4_t acc[8];
#pragma unroll
  for (int ct = 0; ct < 8; ++ct) acc[ct] = (float4_t){0.f, 0.f, 0.f, 0.f};
#pragma unroll
  for (int k0 = 0; k0 < 128; k0 += 32) {
    const int kb = 2 * k0 + hi * 8;
    uint2 alo = *(const uint2*)(Arow + kb);
    uint2 ahi2 = *(const uint2*)(Arow + kb + 32);
    Frag a; a.u = make_uint4(alo.x, alo.y, ahi2.x, ahi2.y);
#pragma unroll
    for (int ct = 0; ct < 8; ++ct) {
      const char* brow = wts + (ct * 16 + lr) * 256;
      uint2 blo = *(const uint2*)(brow + (kb ^ sw));
      uint2 bhi2 = *(const uint2*)(brow + ((kb + 32) ^ sw));
      Frag b; b.u = make_uint4(blo.x, blo.y, bhi2.x, bhi2.y);
      acc[ct] = __builtin_amdgcn_mfma_f32_16x16x32_f16(a.h, b.h, acc[ct], 0, 0, 0);
    }
  }
  int rr[4]; float dnv[4];
#pragma unroll
  for (int reg = 0; reg < 4; ++reg) {
    rr[reg] = row0 + wave * 16 + hi * 4 + reg;
    dnv[reg] = (rr[reg] < n) ? dinv[rr[reg]] : 0.f;
  }
#pragma unroll
  for (int ct = 0; ct < 8; ++ct) {
    int c = ct * 16 + lr;
#pragma unroll
    for (int reg = 0; reg < 4; ++reg)
      if (rr[reg] < n)
        outg[(size_t)rr[reg] * 128 + c] = __float2half(dnv[reg] * acc[ct][reg]);
  }
}

__global__ void __launch_bounds__(256) mfma128x16_kernel(
    const __half* __restrict__ Ah, const char* __restrict__ wt,
    const float* __restrict__ dinv, __half* __restrict__ outg, int n) {
  __shared__ char wts[4096];
  if (threadIdx.x < 256) ((uint4*)wts)[threadIdx.x] = ((const uint4*)wt)[threadIdx.x];
  __syncthreads();
  const int row0 = blockIdx.x * 64;
  const int wave = threadIdx.x >> 6, lane = threadIdx.x & 63;
  const int lr = lane & 15, hi = lane >> 4;
  const int rowL = wave * 16 + lr;
  const char* Arow = (const char*)(Ah + (size_t)(row0 + rowL) * 128);
  const int sw = (lr & 7) << 4;
  const char* brow = wts + lr * 256;
  float4_t acc = (float4_t){0.f, 0.f, 0.f, 0.f};
#pragma unroll
  for (int k0 = 0; k0 < 128; k0 += 32) {
    const int kb = 2 * k0 + hi * 8;
    uint2 alo = *(const uint2*)(Arow + kb);
    uint2 ahi2 = *(const uint2*)(Arow + kb + 32);
    Frag a; a.u = make_uint4(alo.x, alo.y, ahi2.x, ahi2.y);
    uint2 blo = *(const uint2*)(brow + (kb ^ sw));
    uint2 bhi2 = *(const uint2*)(brow + ((kb + 32) ^ sw));
    Frag b; b.u = make_uint4(blo.x, blo.y, bhi2.x, bhi2.y);
    acc = __builtin_amdgcn_mfma_f32_16x16x32_f16(a.h, b.h, acc, 0, 0, 0);
  }
#pragma unroll
  for (int reg = 0; reg < 4; ++reg) {
    int r = row0 + wave * 16 + hi * 4 + reg;
    if (r < n) outg[(size_t)r * 16 + lr] = __float2half(dinv[r] * acc[reg]);
  }
}

__global__ void __launch_bounds__(256) fused_l0l1_kernel(
    const __half* __restrict__ A16h, const float* __restrict__ w0, const float* __restrict__ b0,
    const char* __restrict__ wt1, const float* __restrict__ dinv, __half* __restrict__ g1, int n) {
  __shared__ float a0[64][17];
  __shared__ float ws0[16 * 128];
  __shared__ float bs0[128];
  __shared__ char wts[32768];
  __shared__ char x1s[16384];
  const int row0 = blockIdx.x * 64;
  for (int i = threadIdx.x; i < 2048; i += 256)
    ((uint4*)wts)[i] = ((const uint4*)wt1)[i];
  for (int i = threadIdx.x; i < 512; i += 256)
    ((float4*)ws0)[i] = ((const float4*)w0)[i];
  if (threadIdx.x < 128) bs0[threadIdx.x] = b0[threadIdx.x];
  {
    int r = threadIdx.x >> 2, c8 = threadIdx.x & 3;
    H2U2 v; v.u = make_uint2(0u, 0u);
    if (row0 + r < n) v.u = ((const uint2*)(A16h + (size_t)(row0 + r) * 16))[c8];
    float2 f0 = __half22float2(v.h[0]), f1 = __half22float2(v.h[1]);
    a0[r][c8 * 4 + 0] = f0.x; a0[r][c8 * 4 + 1] = f0.y;
    a0[r][c8 * 4 + 2] = f1.x; a0[r][c8 * 4 + 3] = f1.y;
  }
  __syncthreads();

  {
    const int rg = threadIdx.x >> 4;
    const int c0 = (threadIdx.x & 15) << 3;
    float acc1[4][8];
#pragma unroll
    for (int i = 0; i < 4; ++i)
#pragma unroll
      for (int j = 0; j < 8; ++j) acc1[i][j] = bs0[c0 + j];
#pragma unroll
    for (int k = 0; k < 16; ++k) {
      float A0 = a0[rg * 4 + 0][k], A1 = a0[rg * 4 + 1][k];
      float A2 = a0[rg * 4 + 2][k], A3 = a0[rg * 4 + 3][k];
#pragma unroll
      for (int j = 0; j < 8; ++j) {
        float b = ws0[k * 128 + c0 + j];
        acc1[0][j] = fmaf(A0, b, acc1[0][j]);
        acc1[1][j] = fmaf(A1, b, acc1[1][j]);
        acc1[2][j] = fmaf(A2, b, acc1[2][j]);
        acc1[3][j] = fmaf(A3, b, acc1[3][j]);
      }
    }
#pragma unroll
    for (int i = 0; i < 4; ++i) {
      int row = rg * 4 + i;
      int swz = (row & 7) << 4;
#pragma unroll
      for (int jp = 0; jp < 4; ++jp) {
        int j = jp * 2;
        __half2 h = __float22half2_rn(make_float2(fmaxf(acc1[i][j], 0.f), fmaxf(acc1[i][j + 1], 0.f)));
        *(uint*)(x1s + row * 256 + ((2 * (c0 + j)) ^ swz)) = *(uint*)&h;
      }
    }
  }
  __syncthreads();

  const int wave = threadIdx.x >> 6, lane = threadIdx.x & 63;
  const int lr = lane & 15, hi = lane >> 4;
  const int rowL = wave * 16 + lr;
  const char* Arow = x1s + rowL * 256;
  const int swa = (rowL & 7) << 4;
  const int swb = (lr & 7) << 4;
  float4_t acc[8];
#pragma unroll
  for (int ct = 0; ct < 8; ++ct) acc[ct] = (float4_t){0.f, 0.f, 0.f, 0.f};
#pragma unroll
  for (int k0 = 0; k0 < 128; k0 += 32) {
    const int kb = 2 * k0 + hi * 8;
    uint2 alo = *(const uint2*)(Arow + (kb ^ swa));
    uint2 ahi2 = *(const uint2*)(Arow + ((kb + 32) ^ swa));
    Frag a; a.u = make_uint4(alo.x, alo.y, ahi2.x, ahi2.y);
#pragma unroll
    for (int ct = 0; ct < 8; ++ct) {
      const char* brow = wts + (ct * 16 + lr) * 256;
      uint2 blo = *(const uint2*)(brow + (kb ^ swb));
      uint2 bhi2 = *(const uint2*)(brow + ((kb + 32) ^ swb));
      Frag b; b.u = make_uint4(blo.x, blo.y, bhi2.x, bhi2.y);
      acc[ct] = __builtin_amdgcn_mfma_f32_16x16x32_f16(a.h, b.h, acc[ct], 0, 0, 0);
    }
  }
  int rr[4]; float dnv[4];
#pragma unroll
  for (int reg = 0; reg < 4; ++reg) {
    rr[reg] = row0 + wave * 16 + hi * 4 + reg;
    dnv[reg] = (rr[reg] < n) ? dinv[rr[reg]] : 0.f;
  }
#pragma unroll
  for (int ct = 0; ct < 8; ++ct) {
    int c = ct * 16 + lr;
#pragma unroll
    for (int reg = 0; reg < 4; ++reg)
      if (rr[reg] < n)
        g1[(size_t)rr[reg] * 128 + c] = __float2half(dnv[reg] * acc[ct][reg]);
  }
}

// ---------------------------------------------------------------- launch

extern "C" void kernel_launch(void* const* d_in, const int* in_sizes, int n_in,
                              void* d_out, int out_size, void* d_ws, size_t ws_size,
                              hipStream_t stream) {
  const float* x  = (const float*)d_in[0];
  const int*   ei = (const int*)d_in[1];
  const float* ea = (const float*)d_in[2];
  const float* w0 = (const float*)d_in[3];
  const float* b0 = (const float*)d_in[4];
  const float* w1 = (const float*)d_in[5];
  const float* b1 = (const float*)d_in[6];
  const float* w2 = (const float*)d_in[7];
  const float* b2 = (const float*)d_in[8];
  const float* w3 = (const float*)d_in[9];
  const float* b3 = (const float*)d_in[10];
  float* out = (float*)d_out;

  const int* src = ei;       // edge_index[0]
  const int* dst = ei + NE;  // edge_index[1]

  // workspace: Ah | gbuf | dinv | wt1..3 | csr (16MB) | sorted (8MB) |
  //            blockhist (613KB) | bucket_total  (~51 MB total)
  __half* Ah    = (__half*)d_ws;
  __half* gbuf  = Ah + (size_t)NN * 128;
  float*  dinv  = (float*)(gbuf + (size_t)NN * 128);
  char*   wt1   = (char*)(dinv + ((NN + 63) & ~63));
  char*   wt2   = wt1 + 32768;
  char*   wt3   = wt2 + 32768;
  uint*   csr   = (uint*)(wt3 + 4096);
  uint2*  sorted = (uint2*)(csr + (size_t)NN * ROW_U);
  int*    blockhist = (int*)(sorted + (size_t)NBKT * BCAP);
  int*    bucket_total = blockhist + ((NBKT * NBLK + 15) & ~15);

  const int B = 256;
  const int gb64 = (NN + 63) / 64;  // 782

  // build (atomic-free)
  prep_kernel<<<64, B, 0, stream>>>(w1, w2, w3, wt1, wt2, wt3);
  hist_kernel<<<NBLK, B, 0, stream>>>(dst, blockhist, NE);
  bscan_kernel<<<NBKT, B, 0, stream>>>(blockhist, bucket_total);
  scat_kernel<<<NBLK, B, 0, stream>>>(src, dst, ea, blockhist, sorted, NE);
  build_kernel<<<NBKT, B, 0, stream>>>(sorted, bucket_total, x, csr, dinv, gbuf, NN);

  // layer 0: gather xs(16ch fp16) -> Ah16, fused -> g1 fp16
  gather16_kernel<false><<<(NN + 63) / 64, B, 0, stream>>>(gbuf, csr, dinv, nullptr, Ah, NN);
  fused_l0l1_kernel<<<gb64, B, 0, stream>>>(Ah, w0, b0, wt1, dinv, gbuf, NN);

  // layer 1: gather g1 (+b1, relu) -> Ah fp16 ; MFMA @w2 -> g2
  gather128_kernel<<<(NN + 15) / 16, B, 0, stream>>>(gbuf, csr, dinv, b1, Ah, NN);
  mfma128x128_kernel<<<gb64, B, 0, stream>>>(Ah, wt2, dinv, gbuf, NN);

  // layer 2: gather g2 (+b2, relu) -> Ah ; MFMA @w3 -> g3 (16ch)
  gather128_kernel<<<(NN + 15) / 16, B, 0, stream>>>(gbuf, csr, dinv, b2, Ah, NN);
  mfma128x16_kernel<<<gb64, B, 0, stream>>>(Ah, wt3, dinv, gbuf, NN);

  // layer 3: final gather (+b3) -> out fp32
  gather16_kernel<true><<<(NN + 63) / 64, B, 0, stream>>>(gbuf, csr, dinv, b3, out, NN);
}